// Round 5
// baseline (550.549 us; speedup 1.0000x reference)
//
#include <hip/hip_runtime.h>

#define N_NODES 100000
#define N_EDGES 3200000
#define N_QUADS (N_EDGES / 4)            // 800000

#define NB      256                      // blocks = CUs; 1 block/CU forced by LDS
#define T       1024
#define P_PARTS 4
#define PART    25600                    // 4*25600 = 102400 >= N ; 102.4 KB LDS
#define SLICES  64
#define SLICE_Q (N_QUADS / SLICES)       // 12500 quads per slice

// ---------------- workspace layout (bytes) ----------------
#define OFF_BAR   0        // unsigned[4] grid-barrier counters (zeroed per iter)
#define OFF_SPART 1024     // double[NB*5] stats partials
#define OFF_DEG   11264    // float[N]
#define OFF_ACC   411264   // float[N]
#define OFF_DINV  811264   // float[N]
#define OFF_GS    1211264  // float[N]
#define OFF_SRC32 1611264  // int[N_EDGES] 12.8MB
#define OFF_DST32 14411264 // int[N_EDGES] 12.8MB -> 27,211,264 total

// per-wave int64-vs-int32 detection: high words of first 64 int64 slots
__device__ __forceinline__ bool detect_is64(const void* ei) {
    const int* p = (const int*)ei;
    int lane = threadIdx.x & 63;
    int hi = p[2 * lane + 1];
    unsigned long long m = __ballot(hi != 0);
    return m == 0ull;  // wave-uniform
}

// software grid barrier: all NB blocks co-resident (1 block/CU by LDS).
// release: threadfence before arrive; acquire: atomic-load spin + threadfence after.
__device__ __forceinline__ void grid_bar(unsigned* bar) {
    __syncthreads();
    if (threadIdx.x == 0) {
        __threadfence();
        __hip_atomic_fetch_add(bar, 1u, __ATOMIC_ACQ_REL, __HIP_MEMORY_SCOPE_AGENT);
        while (__hip_atomic_load(bar, __ATOMIC_ACQUIRE, __HIP_MEMORY_SCOPE_AGENT) < (unsigned)NB)
            __builtin_amdgcn_s_sleep(8);
    }
    __syncthreads();
    __threadfence();
}

__global__ __launch_bounds__(T, 4) void mega_kernel(
        const float* __restrict__ x, const void* __restrict__ ei,
        const float* __restrict__ w1, const float* __restrict__ b1,
        const float* __restrict__ gamma, const float* __restrict__ beta,
        const float* __restrict__ prelu_a,
        const float* __restrict__ w2, const float* __restrict__ b2,
        const float* __restrict__ gcn_w, const float* __restrict__ gcn_b,
        const float* __restrict__ wb, const float* __restrict__ bb,
        char* __restrict__ ws, float* __restrict__ out) {
    __shared__ float hist[PART];         // 102.4 KB -> exactly 1 block/CU
    __shared__ double sh[5][T / 64];
    __shared__ double sStats[5];
    __shared__ float sA[32], sB[32], sC[32], sV[32], sU[32];
    __shared__ float sGB, sSCC;

    unsigned* bar   = (unsigned*)(ws + OFF_BAR);
    double*   spart = (double*)(ws + OFF_SPART);
    float*    degf  = (float*)(ws + OFF_DEG);
    float*    acc   = (float*)(ws + OFF_ACC);
    float*    dinv  = (float*)(ws + OFF_DINV);
    float*    gs    = (float*)(ws + OFF_GS);
    int*      src32 = (int*)(ws + OFF_SRC32);
    int*      dst32 = (int*)(ws + OFF_DST32);

    const int tid  = threadIdx.x;
    const int bid  = blockIdx.x;
    const int gtid = bid * T + tid;
    bool is64 = detect_is64(ei);

    // ================= P0: pack edges + zero degf + BN stats partials ==========
    if (is64) {
        const long long* srcp = (const long long*)ei;
        const long long* dstp = srcp + N_EDGES;
        for (int q = gtid; q < N_QUADS; q += NB * T) {
            longlong2 s01 = ((const longlong2*)srcp)[2 * q];
            longlong2 s23 = ((const longlong2*)srcp)[2 * q + 1];
            longlong2 d01 = ((const longlong2*)dstp)[2 * q];
            longlong2 d23 = ((const longlong2*)dstp)[2 * q + 1];
            ((int4*)src32)[q] = make_int4((int)s01.x, (int)s01.y, (int)s23.x, (int)s23.y);
            ((int4*)dst32)[q] = make_int4((int)d01.x, (int)d01.y, (int)d23.x, (int)d23.y);
        }
    } else {
        const int* srcp = (const int*)ei;
        const int* dstp = srcp + N_EDGES;
        for (int q = gtid; q < N_QUADS; q += NB * T) {
            ((int4*)src32)[q] = ((const int4*)srcp)[q];
            ((int4*)dst32)[q] = ((const int4*)dstp)[q];
        }
    }
    if (gtid < N_NODES) degf[gtid] = 0.f;   // NB*T = 262144 >= N

    {   // per-block stats partial (all blocks write, zero if out of range)
        double a0 = 0, a1 = 0, a2 = 0, a3 = 0, a4 = 0;
        if (gtid < N_NODES) {
            float2 v = ((const float2*)x)[gtid];
            double x0 = v.x, x1 = v.y;
            a0 = x0; a1 = x1; a2 = x0 * x0; a3 = x1 * x1; a4 = x0 * x1;
        }
        for (int off = 32; off; off >>= 1) {
            a0 += __shfl_down(a0, off);
            a1 += __shfl_down(a1, off);
            a2 += __shfl_down(a2, off);
            a3 += __shfl_down(a3, off);
            a4 += __shfl_down(a4, off);
        }
        int w = tid >> 6;
        if ((tid & 63) == 0) {
            sh[0][w] = a0; sh[1][w] = a1; sh[2][w] = a2; sh[3][w] = a3; sh[4][w] = a4;
        }
        __syncthreads();
        if (tid == 0) {
            double t0 = 0, t1 = 0, t2 = 0, t3 = 0, t4 = 0;
            for (int i = 0; i < T / 64; i++) {
                t0 += sh[0][i]; t1 += sh[1][i]; t2 += sh[2][i]; t3 += sh[3][i]; t4 += sh[4][i];
            }
            double* sp = &spart[bid * 5];
            sp[0] = t0; sp[1] = t1; sp[2] = t2; sp[3] = t3; sp[4] = t4;
        }
    }
    grid_bar(&bar[0]);

    // ================= P1: degree histogram (P=4, 4x ILP unroll) ==============
    {
        const int p = bid & (P_PARTS - 1);
        const int slice = bid >> 2;
        const int base = p * PART;
        for (int i = tid; i < PART; i += T) hist[i] = 0.f;
        __syncthreads();
        const int4* dq = (const int4*)dst32;
        int q0 = slice * SLICE_Q, q1 = q0 + SLICE_Q;
#define DG4(V) { \
        unsigned l0 = (unsigned)((V).x - base); \
        unsigned l1 = (unsigned)((V).y - base); \
        unsigned l2 = (unsigned)((V).z - base); \
        unsigned l3 = (unsigned)((V).w - base); \
        if (l0 < PART) atomicAdd(&hist[l0], 1.0f); \
        if (l1 < PART) atomicAdd(&hist[l1], 1.0f); \
        if (l2 < PART) atomicAdd(&hist[l2], 1.0f); \
        if (l3 < PART) atomicAdd(&hist[l3], 1.0f); }
        int qb = q0;
        for (; qb + 4 * T <= q1; qb += 4 * T) {
            int4 a = dq[qb + tid];
            int4 b = dq[qb + T + tid];
            int4 c = dq[qb + 2 * T + tid];
            int4 d = dq[qb + 3 * T + tid];
            DG4(a) DG4(b) DG4(c) DG4(d)
        }
        for (int q = qb + tid; q < q1; q += T) { int4 a = dq[q]; DG4(a) }
#undef DG4
        __syncthreads();
        for (int i = tid; i < PART; i += T) {
            float v = hist[i];
            int n = base + i;
            if (v != 0.f && n < N_NODES) unsafeAtomicAdd(&degf[n], v);
        }
    }
    grid_bar(&bar[1]);

    // ================= P2: encoder ============================================
    {
        if (tid < 64) {   // reduce stats partials (NB*5 doubles)
            double p0 = 0, p1 = 0, p2 = 0, p3 = 0, p4 = 0;
            for (int j = tid; j < NB; j += 64) {
                const double* sp = &spart[j * 5];
                p0 += sp[0]; p1 += sp[1]; p2 += sp[2]; p3 += sp[3]; p4 += sp[4];
            }
            for (int off = 32; off; off >>= 1) {
                p0 += __shfl_down(p0, off);
                p1 += __shfl_down(p1, off);
                p2 += __shfl_down(p2, off);
                p3 += __shfl_down(p3, off);
                p4 += __shfl_down(p4, off);
            }
            if (tid == 0) {
                sStats[0] = p0; sStats[1] = p1; sStats[2] = p2; sStats[3] = p3; sStats[4] = p4;
            }
        }
        __syncthreads();
        if (tid < 32) {
            int c = tid;
            double invN = 1.0 / (double)N_NODES;
            double m0 = sStats[0] * invN, m1 = sStats[1] * invN;
            double e00 = sStats[2] * invN, e11 = sStats[3] * invN, e01 = sStats[4] * invN;
            double a = w1[2 * c], b = w1[2 * c + 1], t = b1[c];
            double meanH = a * m0 + b * m1 + t;
            double eh2 = a * a * e00 + b * b * e11 + 2.0 * a * b * e01 +
                         2.0 * t * (a * m0 + b * m1) + t * t;
            double var = eh2 - meanH * meanH;
            double inv = 1.0 / sqrt(var + 1e-5);
            float sc = (float)((double)gamma[c] * inv);
            float shift = beta[c] - (float)meanH * sc;
            sA[c] = (float)a * sc;
            sB[c] = (float)b * sc;
            sC[c] = (float)t * sc + shift;
            float vc = 0.f;
            for (int j = 0; j < 32; j++) vc += wb[j] * gcn_w[j * 32 + c];
            sV[c] = vc;
            float gb = b2[c] * vc;
            for (int off = 16; off; off >>= 1) gb += __shfl_down(gb, off, 32);
            if (c == 0) sGB = gb;
        }
        __syncthreads();
        if (tid < 32) {
            float u = 0.f;
            for (int c = 0; c < 32; c++) u += sV[c] * w2[c * 32 + tid];
            sU[tid] = u;
        }
        __syncthreads();
        float alpha = prelu_a[0];
        if (gtid < N_NODES) {
            float2 xv = ((const float2*)x)[gtid];
            float g = sGB;
#pragma unroll
            for (int c = 0; c < 32; c++) {
                float hb = sA[c] * xv.x + sB[c] * xv.y + sC[c];
                float pc = hb >= 0.f ? hb : alpha * hb;
                g += pc * sU[c];
            }
            float di = rsqrtf(degf[gtid] + 1.0f);
            float gg = di * g;
            dinv[gtid] = di;
            gs[gtid] = gg;
            acc[gtid] = gg;   // self-loop term; finalize multiplies by dinv
        }
    }
    grid_bar(&bar[2]);

    // ================= P3: scatter histogram (P=4, 4x ILP unroll) =============
    {
        const int p = bid & (P_PARTS - 1);
        const int slice = bid >> 2;
        const int base = p * PART;
        for (int i = tid; i < PART; i += T) hist[i] = 0.f;
        __syncthreads();
        const int4* dq = (const int4*)dst32;
        const int4* sq = (const int4*)src32;
        int q0 = slice * SLICE_Q, q1 = q0 + SLICE_Q;
#define SC4(D, S) { \
        unsigned l0 = (unsigned)((D).x - base); \
        unsigned l1 = (unsigned)((D).y - base); \
        unsigned l2 = (unsigned)((D).z - base); \
        unsigned l3 = (unsigned)((D).w - base); \
        if (l0 < PART) atomicAdd(&hist[l0], gs[(S).x]); \
        if (l1 < PART) atomicAdd(&hist[l1], gs[(S).y]); \
        if (l2 < PART) atomicAdd(&hist[l2], gs[(S).z]); \
        if (l3 < PART) atomicAdd(&hist[l3], gs[(S).w]); }
        int qb = q0;
        for (; qb + 4 * T <= q1; qb += 4 * T) {
            int4 da = dq[qb + tid];
            int4 db = dq[qb + T + tid];
            int4 dc = dq[qb + 2 * T + tid];
            int4 dd = dq[qb + 3 * T + tid];
            int4 sa = sq[qb + tid];
            int4 sb = sq[qb + T + tid];
            int4 sc = sq[qb + 2 * T + tid];
            int4 sd = sq[qb + 3 * T + tid];
            SC4(da, sa) SC4(db, sb) SC4(dc, sc) SC4(dd, sd)
        }
        for (int q = qb + tid; q < q1; q += T) {
            int4 da = dq[q];
            int4 sa = sq[q];
            SC4(da, sa)
        }
#undef SC4
        __syncthreads();
        for (int i = tid; i < PART; i += T) {
            float v = hist[i];
            int n = base + i;
            if (v != 0.f && n < N_NODES) unsafeAtomicAdd(&acc[n], v);
        }
    }
    grid_bar(&bar[3]);

    // ================= P4: finalize ===========================================
    {
        if (tid < 32) {
            float pv = wb[tid] * gcn_b[tid];
            for (int off = 16; off; off >>= 1) pv += __shfl_down(pv, off, 32);
            if (tid == 0) sSCC = pv + bb[0];
        }
        __syncthreads();
        if (gtid < N_NODES) out[gtid] = dinv[gtid] * acc[gtid] + sSCC;
    }
}

extern "C" void kernel_launch(void* const* d_in, const int* in_sizes, int n_in,
                              void* d_out, int out_size, void* d_ws, size_t ws_size,
                              hipStream_t stream) {
    const float* x       = (const float*)d_in[0];
    const void*  ei      = d_in[1];
    const float* w1      = (const float*)d_in[2];
    const float* b1      = (const float*)d_in[3];
    const float* bn_g    = (const float*)d_in[4];
    const float* bn_b    = (const float*)d_in[5];
    const float* prelu_a = (const float*)d_in[6];
    const float* w2      = (const float*)d_in[7];
    const float* b2      = (const float*)d_in[8];
    const float* gcn_w   = (const float*)d_in[9];
    const float* gcn_b   = (const float*)d_in[10];
    const float* wb      = (const float*)d_in[11];
    const float* bb      = (const float*)d_in[12];
    float* out = (float*)d_out;

    // zero only the 4 barrier counters (64 B) each iteration
    hipMemsetAsync(d_ws, 0, 64, stream);

    mega_kernel<<<NB, T, 0, stream>>>(
        x, ei, w1, b1, bn_g, bn_b, prelu_a, w2, b2, gcn_w, gcn_b, wb, bb,
        (char*)d_ws, out);
}

// Round 8
// 191.197 us; speedup vs baseline: 2.8795x; 2.8795x over previous
//
#include <hip/hip_runtime.h>

#define N_NODES 100000
#define N_EDGES 3200000
#define N_QUADS (N_EDGES / 4)            // 800000

// ---- hist geometry: P=4 partitions, 64 slices, 256 blocks, 1 block/CU ----
#define P_PARTS  4
#define PART     25600                   // 4*25600 = 102400 >= N ; 102.4 KB LDS
#define SLICES   64
#define SLICE_Q  (N_QUADS / SLICES)      // 12500 quads per slice (exact)
#define BLOCKS_H (P_PARTS * SLICES)      // 256
#define T_HIST   1024

// ---------------- workspace layout (bytes) ----------------
#define OFF_STATS 0                      // double[5] (zeroed)
#define OFF_DEG   1024                   // float[102400] (zeroed)
#define OFF_ACC   410624                 // float[102400] (encoder writes [0,N))
#define OFF_DINV  820224                 // float[N]
#define OFF_GS    1220224                // float[N]
// total ~1.62 MB

// per-wave int64-vs-int32 detection: high words of first 64 int64 slots
__device__ __forceinline__ bool detect_is64(const void* ei) {
    const int* p = (const int*)ei;
    int lane = threadIdx.x & 63;
    int hi = p[2 * lane + 1];
    unsigned long long m = __ballot(hi != 0);
    return m == 0ull;  // wave-uniform
}

// ---- K1: degree histogram straight from int64 dst + BN stats ----
__global__ __launch_bounds__(T_HIST) void stats_deg_kernel(
        const float* __restrict__ x, const void* __restrict__ ei,
        double* __restrict__ stats, float* __restrict__ degf) {
    __shared__ float hist[PART];
    bool is64 = detect_is64(ei);
    const int tid = threadIdx.x;
    const int p = blockIdx.x & (P_PARTS - 1);
    const int slice = blockIdx.x >> 2;
    const int base = p * PART;

    for (int i = tid; i < PART; i += T_HIST) hist[i] = 0.f;
    __syncthreads();

    int q0 = slice * SLICE_Q, q1 = q0 + SLICE_Q;
#define DGE(va, vb) { \
        unsigned l0 = (unsigned)((int)(va).x - base); \
        unsigned l1 = (unsigned)((int)(va).y - base); \
        unsigned l2 = (unsigned)((int)(vb).x - base); \
        unsigned l3 = (unsigned)((int)(vb).y - base); \
        if (l0 < PART) atomicAdd(&hist[l0], 1.0f); \
        if (l1 < PART) atomicAdd(&hist[l1], 1.0f); \
        if (l2 < PART) atomicAdd(&hist[l2], 1.0f); \
        if (l3 < PART) atomicAdd(&hist[l3], 1.0f); }
    if (is64) {
        const longlong2* dq = (const longlong2*)((const long long*)ei + N_EDGES);
        int qb = q0;
        for (; qb + 4 * T_HIST <= q1; qb += 4 * T_HIST) {
            longlong2 a0 = dq[2 * (qb + tid)],              a1 = dq[2 * (qb + tid) + 1];
            longlong2 b0 = dq[2 * (qb + T_HIST + tid)],     b1 = dq[2 * (qb + T_HIST + tid) + 1];
            longlong2 c0 = dq[2 * (qb + 2 * T_HIST + tid)], c1 = dq[2 * (qb + 2 * T_HIST + tid) + 1];
            longlong2 d0 = dq[2 * (qb + 3 * T_HIST + tid)], d1 = dq[2 * (qb + 3 * T_HIST + tid) + 1];
            DGE(a0, a1) DGE(b0, b1) DGE(c0, c1) DGE(d0, d1)
        }
        for (int q = qb + tid; q < q1; q += T_HIST) {
            longlong2 a0 = dq[2 * q], a1 = dq[2 * q + 1];
            DGE(a0, a1)
        }
    } else {
        const int4* dq = (const int4*)((const int*)ei + N_EDGES);
        int qb = q0;
#define DG4(V) { \
        unsigned l0 = (unsigned)((V).x - base); \
        unsigned l1 = (unsigned)((V).y - base); \
        unsigned l2 = (unsigned)((V).z - base); \
        unsigned l3 = (unsigned)((V).w - base); \
        if (l0 < PART) atomicAdd(&hist[l0], 1.0f); \
        if (l1 < PART) atomicAdd(&hist[l1], 1.0f); \
        if (l2 < PART) atomicAdd(&hist[l2], 1.0f); \
        if (l3 < PART) atomicAdd(&hist[l3], 1.0f); }
        for (; qb + 4 * T_HIST <= q1; qb += 4 * T_HIST) {
            int4 a = dq[qb + tid];
            int4 b = dq[qb + T_HIST + tid];
            int4 c = dq[qb + 2 * T_HIST + tid];
            int4 d = dq[qb + 3 * T_HIST + tid];
            DG4(a) DG4(b) DG4(c) DG4(d)
        }
        for (int q = qb + tid; q < q1; q += T_HIST) { int4 a = dq[q]; DG4(a) }
#undef DG4
    }
#undef DGE
    __syncthreads();
    // flush: consecutive addresses -> coalescable global atomics; zero-skip
    for (int i = tid; i < PART; i += T_HIST) {
        float v = hist[i];
        if (v != 0.f) unsafeAtomicAdd(&degf[base + i], v);
    }

    // ---- BN stats over x (blocks covering node range only; block-uniform guard) ----
    if (blockIdx.x * T_HIST < N_NODES) {
        __shared__ double sh[5][T_HIST / 64];
        int n = blockIdx.x * T_HIST + tid;
        double a0 = 0, a1 = 0, a2 = 0, a3 = 0, a4 = 0;
        if (n < N_NODES) {
            float2 v = ((const float2*)x)[n];
            double x0 = v.x, x1 = v.y;
            a0 = x0; a1 = x1; a2 = x0 * x0; a3 = x1 * x1; a4 = x0 * x1;
        }
        for (int off = 32; off; off >>= 1) {
            a0 += __shfl_down(a0, off);
            a1 += __shfl_down(a1, off);
            a2 += __shfl_down(a2, off);
            a3 += __shfl_down(a3, off);
            a4 += __shfl_down(a4, off);
        }
        int w = tid >> 6;
        if ((tid & 63) == 0) {
            sh[0][w] = a0; sh[1][w] = a1; sh[2][w] = a2; sh[3][w] = a3; sh[4][w] = a4;
        }
        __syncthreads();
        if (tid == 0) {
            double t0 = 0, t1 = 0, t2 = 0, t3 = 0, t4 = 0;
            for (int i = 0; i < T_HIST / 64; i++) {
                t0 += sh[0][i]; t1 += sh[1][i]; t2 += sh[2][i]; t3 += sh[3][i]; t4 += sh[4][i];
            }
            atomicAdd(&stats[0], t0);
            atomicAdd(&stats[1], t1);
            atomicAdd(&stats[2], t2);
            atomicAdd(&stats[3], t3);
            atomicAdd(&stats[4], t4);
        }
    }
}

// ---- K2: encoder: gs[n] = dinv * (GB + sum_c PReLU(Ax0+Bx1+C) U[c]) ----
__global__ void encoder_kernel(const float* __restrict__ x,
                               const double* __restrict__ stats,
                               const float* __restrict__ w1, const float* __restrict__ b1,
                               const float* __restrict__ gamma, const float* __restrict__ beta,
                               const float* __restrict__ prelu_a,
                               const float* __restrict__ w2, const float* __restrict__ b2,
                               const float* __restrict__ gcn_w, const float* __restrict__ wb,
                               const float* __restrict__ degf,
                               float* __restrict__ dinv, float* __restrict__ gs,
                               float* __restrict__ acc) {
    __shared__ float sA[32], sB[32], sC[32], sV[32], sU[32];
    __shared__ float sGB;
    if (threadIdx.x < 32) {
        int c = threadIdx.x;
        double invN = 1.0 / (double)N_NODES;
        double m0 = stats[0] * invN, m1 = stats[1] * invN;
        double e00 = stats[2] * invN, e11 = stats[3] * invN, e01 = stats[4] * invN;
        double a = w1[2 * c], b = w1[2 * c + 1], t = b1[c];
        double meanH = a * m0 + b * m1 + t;
        double eh2 = a * a * e00 + b * b * e11 + 2.0 * a * b * e01 +
                     2.0 * t * (a * m0 + b * m1) + t * t;
        double var = eh2 - meanH * meanH;
        double inv = 1.0 / sqrt(var + 1e-5);
        float sc = (float)((double)gamma[c] * inv);
        float shift = beta[c] - (float)meanH * sc;
        sA[c] = (float)a * sc;
        sB[c] = (float)b * sc;
        sC[c] = (float)t * sc + shift;
        float vc = 0.f;
        for (int j = 0; j < 32; j++) vc += wb[j] * gcn_w[j * 32 + c];
        sV[c] = vc;
        float gb = b2[c] * vc;
        for (int off = 16; off; off >>= 1) gb += __shfl_down(gb, off, 32);
        if (c == 0) sGB = gb;
    }
    __syncthreads();
    if (threadIdx.x < 32) {
        float u = 0.f;
        for (int c = 0; c < 32; c++) u += sV[c] * w2[c * 32 + threadIdx.x];
        sU[threadIdx.x] = u;
    }
    __syncthreads();
    float alpha = prelu_a[0];
    int n = blockIdx.x * blockDim.x + threadIdx.x;
    if (n < N_NODES) {
        float2 xv = ((const float2*)x)[n];
        float g = sGB;
#pragma unroll
        for (int c = 0; c < 32; c++) {
            float hb = sA[c] * xv.x + sB[c] * xv.y + sC[c];
            float pc = hb >= 0.f ? hb : alpha * hb;
            g += pc * sU[c];
        }
        float di = rsqrtf(degf[n] + 1.0f);
        float gg = di * g;
        dinv[n] = di;
        gs[n] = gg;
        acc[n] = gg;  // self-loop term; finalize multiplies by dinv
    }
}

// ---- K3: scatter histogram straight from int64 src/dst ----
__global__ __launch_bounds__(T_HIST) void scatter_kernel(
        const void* __restrict__ ei, const float* __restrict__ gs,
        float* __restrict__ acc) {
    __shared__ float hist[PART];
    bool is64 = detect_is64(ei);
    const int tid = threadIdx.x;
    const int p = blockIdx.x & (P_PARTS - 1);
    const int slice = blockIdx.x >> 2;
    const int base = p * PART;

    for (int i = tid; i < PART; i += T_HIST) hist[i] = 0.f;
    __syncthreads();

    int q0 = slice * SLICE_Q, q1 = q0 + SLICE_Q;
    if (is64) {
        const longlong2* sq = (const longlong2*)((const long long*)ei);
        const longlong2* dq = (const longlong2*)((const long long*)ei + N_EDGES);
#define SCE(sa, sb, da, db) { \
        unsigned l0 = (unsigned)((int)(da).x - base); \
        unsigned l1 = (unsigned)((int)(da).y - base); \
        unsigned l2 = (unsigned)((int)(db).x - base); \
        unsigned l3 = (unsigned)((int)(db).y - base); \
        if (l0 < PART) atomicAdd(&hist[l0], gs[(int)(sa).x]); \
        if (l1 < PART) atomicAdd(&hist[l1], gs[(int)(sa).y]); \
        if (l2 < PART) atomicAdd(&hist[l2], gs[(int)(sb).x]); \
        if (l3 < PART) atomicAdd(&hist[l3], gs[(int)(sb).y]); }
        int qb = q0;
        for (; qb + 2 * T_HIST <= q1; qb += 2 * T_HIST) {
            longlong2 sa0 = sq[2 * (qb + tid)],          sa1 = sq[2 * (qb + tid) + 1];
            longlong2 da0 = dq[2 * (qb + tid)],          da1 = dq[2 * (qb + tid) + 1];
            longlong2 sb0 = sq[2 * (qb + T_HIST + tid)], sb1 = sq[2 * (qb + T_HIST + tid) + 1];
            longlong2 db0 = dq[2 * (qb + T_HIST + tid)], db1 = dq[2 * (qb + T_HIST + tid) + 1];
            SCE(sa0, sa1, da0, da1)
            SCE(sb0, sb1, db0, db1)
        }
        for (int q = qb + tid; q < q1; q += T_HIST) {
            longlong2 sa0 = sq[2 * q], sa1 = sq[2 * q + 1];
            longlong2 da0 = dq[2 * q], da1 = dq[2 * q + 1];
            SCE(sa0, sa1, da0, da1)
        }
#undef SCE
    } else {
        const int4* sq = (const int4*)((const int*)ei);
        const int4* dq = (const int4*)((const int*)ei + N_EDGES);
#define SC4(S, D) { \
        unsigned l0 = (unsigned)((D).x - base); \
        unsigned l1 = (unsigned)((D).y - base); \
        unsigned l2 = (unsigned)((D).z - base); \
        unsigned l3 = (unsigned)((D).w - base); \
        if (l0 < PART) atomicAdd(&hist[l0], gs[(S).x]); \
        if (l1 < PART) atomicAdd(&hist[l1], gs[(S).y]); \
        if (l2 < PART) atomicAdd(&hist[l2], gs[(S).z]); \
        if (l3 < PART) atomicAdd(&hist[l3], gs[(S).w]); }
        int qb = q0;
        for (; qb + 2 * T_HIST <= q1; qb += 2 * T_HIST) {
            int4 sa = sq[qb + tid];
            int4 da = dq[qb + tid];
            int4 sb = sq[qb + T_HIST + tid];
            int4 db = dq[qb + T_HIST + tid];
            SC4(sa, da) SC4(sb, db)
        }
        for (int q = qb + tid; q < q1; q += T_HIST) {
            int4 sa = sq[q];
            int4 da = dq[q];
            SC4(sa, da)
        }
#undef SC4
    }
    __syncthreads();
    for (int i = tid; i < PART; i += T_HIST) {
        float v = hist[i];
        if (v != 0.f) unsafeAtomicAdd(&acc[base + i], v);
    }
}

// ---- K4: finalize: out = dinv*acc + const ----
__global__ void finalize_kernel(const float* __restrict__ dinv, const float* __restrict__ acc,
                                const float* __restrict__ gcn_b, const float* __restrict__ wb,
                                const float* __restrict__ bb, float* __restrict__ out) {
    __shared__ float scc;
    if (threadIdx.x < 32) {
        float pv = wb[threadIdx.x] * gcn_b[threadIdx.x];
        for (int off = 16; off; off >>= 1) pv += __shfl_down(pv, off, 32);
        if (threadIdx.x == 0) scc = pv + bb[0];
    }
    __syncthreads();
    int n = blockIdx.x * blockDim.x + threadIdx.x;
    if (n < N_NODES) out[n] = dinv[n] * acc[n] + scc;
}

extern "C" void kernel_launch(void* const* d_in, const int* in_sizes, int n_in,
                              void* d_out, int out_size, void* d_ws, size_t ws_size,
                              hipStream_t stream) {
    const float* x       = (const float*)d_in[0];
    const void*  ei      = d_in[1];
    const float* w1      = (const float*)d_in[2];
    const float* b1      = (const float*)d_in[3];
    const float* bn_g    = (const float*)d_in[4];
    const float* bn_b    = (const float*)d_in[5];
    const float* prelu_a = (const float*)d_in[6];
    const float* w2      = (const float*)d_in[7];
    const float* b2      = (const float*)d_in[8];
    const float* gcn_w   = (const float*)d_in[9];
    const float* gcn_b   = (const float*)d_in[10];
    const float* wb      = (const float*)d_in[11];
    const float* bb      = (const float*)d_in[12];
    float* out = (float*)d_out;

    char* base = (char*)d_ws;
    double* stats = (double*)(base + OFF_STATS);
    float*  degf  = (float*)(base + OFF_DEG);
    float*  acc   = (float*)(base + OFF_ACC);
    float*  dinv  = (float*)(base + OFF_DINV);
    float*  gs    = (float*)(base + OFF_GS);

    // zero stats + degf (acc[0,N) fully written by encoder; hist zero-skip covers the rest)
    hipMemsetAsync(d_ws, 0, OFF_DEG + PART * P_PARTS * 4, stream);

    stats_deg_kernel<<<BLOCKS_H, T_HIST, 0, stream>>>(x, ei, stats, degf);
    encoder_kernel<<<(N_NODES + 255) / 256, 256, 0, stream>>>(
        x, stats, w1, b1, bn_g, bn_b, prelu_a, w2, b2, gcn_w, wb, degf, dinv, gs, acc);
    scatter_kernel<<<BLOCKS_H, T_HIST, 0, stream>>>(ei, gs, acc);
    finalize_kernel<<<(N_NODES + 255) / 256, 256, 0, stream>>>(dinv, acc, gcn_b, wb, bb, out);
}

// Round 9
// 185.347 us; speedup vs baseline: 2.9704x; 1.0316x over previous
//
#include <hip/hip_runtime.h>

#define N_NODES 100000
#define N_EDGES 3200000
#define N_QUADS (N_EDGES / 4)            // 800000

// ---- hist geometry: P=4 partitions, 64 slices, 256 blocks, 1 block/CU ----
// XCD-locality: p = bid>>6, slice = bid&63 -> same-slice blocks are bids
// {s, s+64, s+128, s+192}; 64%8==0 so all four land on the same XCD and the
// slice's edge data is L2-resident after first touch (4MB/XCD L2, slice<=1.6MB).
#define P_PARTS  4
#define PART     25600                   // 4*25600 = 102400 >= N ; 102.4 KB LDS
#define SLICES   64
#define SLICE_Q  (N_QUADS / SLICES)      // 12500 quads per slice (exact)
#define BLOCKS_H (P_PARTS * SLICES)      // 256
#define T_HIST   1024

// ---------------- workspace layout (bytes) ----------------
#define OFF_STATS 0                      // double[5] (zeroed)
#define OFF_DEG   1024                   // float[102400] (zeroed)
#define OFF_ACC   410624                 // float[102400] (encoder writes [0,N))
#define OFF_DINV  820224                 // float[N]
#define OFF_GS    1220224                // float[N]
// total ~1.62 MB

// per-wave int64-vs-int32 detection: high words of first 64 int64 slots
__device__ __forceinline__ bool detect_is64(const void* ei) {
    const int* p = (const int*)ei;
    int lane = threadIdx.x & 63;
    int hi = p[2 * lane + 1];
    unsigned long long m = __ballot(hi != 0);
    return m == 0ull;  // wave-uniform
}

// ---- K1: degree histogram straight from int64 dst + BN stats ----
__global__ __launch_bounds__(T_HIST) void stats_deg_kernel(
        const float* __restrict__ x, const void* __restrict__ ei,
        double* __restrict__ stats, float* __restrict__ degf) {
    __shared__ float hist[PART];
    bool is64 = detect_is64(ei);
    const int tid = threadIdx.x;
    const int p = blockIdx.x >> 6;       // XCD-locality mapping (was bid&3)
    const int slice = blockIdx.x & 63;   // (was bid>>2)
    const int base = p * PART;

    for (int i = tid; i < PART; i += T_HIST) hist[i] = 0.f;
    __syncthreads();

    int q0 = slice * SLICE_Q, q1 = q0 + SLICE_Q;
#define DGE(va, vb) { \
        unsigned l0 = (unsigned)((int)(va).x - base); \
        unsigned l1 = (unsigned)((int)(va).y - base); \
        unsigned l2 = (unsigned)((int)(vb).x - base); \
        unsigned l3 = (unsigned)((int)(vb).y - base); \
        if (l0 < PART) atomicAdd(&hist[l0], 1.0f); \
        if (l1 < PART) atomicAdd(&hist[l1], 1.0f); \
        if (l2 < PART) atomicAdd(&hist[l2], 1.0f); \
        if (l3 < PART) atomicAdd(&hist[l3], 1.0f); }
    if (is64) {
        const longlong2* dq = (const longlong2*)((const long long*)ei + N_EDGES);
        int qb = q0;
        for (; qb + 4 * T_HIST <= q1; qb += 4 * T_HIST) {
            longlong2 a0 = dq[2 * (qb + tid)],              a1 = dq[2 * (qb + tid) + 1];
            longlong2 b0 = dq[2 * (qb + T_HIST + tid)],     b1 = dq[2 * (qb + T_HIST + tid) + 1];
            longlong2 c0 = dq[2 * (qb + 2 * T_HIST + tid)], c1 = dq[2 * (qb + 2 * T_HIST + tid) + 1];
            longlong2 d0 = dq[2 * (qb + 3 * T_HIST + tid)], d1 = dq[2 * (qb + 3 * T_HIST + tid) + 1];
            DGE(a0, a1) DGE(b0, b1) DGE(c0, c1) DGE(d0, d1)
        }
        for (int q = qb + tid; q < q1; q += T_HIST) {
            longlong2 a0 = dq[2 * q], a1 = dq[2 * q + 1];
            DGE(a0, a1)
        }
    } else {
        const int4* dq = (const int4*)((const int*)ei + N_EDGES);
        int qb = q0;
#define DG4(V) { \
        unsigned l0 = (unsigned)((V).x - base); \
        unsigned l1 = (unsigned)((V).y - base); \
        unsigned l2 = (unsigned)((V).z - base); \
        unsigned l3 = (unsigned)((V).w - base); \
        if (l0 < PART) atomicAdd(&hist[l0], 1.0f); \
        if (l1 < PART) atomicAdd(&hist[l1], 1.0f); \
        if (l2 < PART) atomicAdd(&hist[l2], 1.0f); \
        if (l3 < PART) atomicAdd(&hist[l3], 1.0f); }
        for (; qb + 4 * T_HIST <= q1; qb += 4 * T_HIST) {
            int4 a = dq[qb + tid];
            int4 b = dq[qb + T_HIST + tid];
            int4 c = dq[qb + 2 * T_HIST + tid];
            int4 d = dq[qb + 3 * T_HIST + tid];
            DG4(a) DG4(b) DG4(c) DG4(d)
        }
        for (int q = qb + tid; q < q1; q += T_HIST) { int4 a = dq[q]; DG4(a) }
#undef DG4
    }
#undef DGE
    __syncthreads();
    // flush: consecutive addresses -> coalescable global atomics; zero-skip
    for (int i = tid; i < PART; i += T_HIST) {
        float v = hist[i];
        if (v != 0.f) unsafeAtomicAdd(&degf[base + i], v);
    }

    // ---- BN stats over x (blocks covering node range only; block-uniform guard) ----
    if (blockIdx.x * T_HIST < N_NODES) {
        __shared__ double sh[5][T_HIST / 64];
        int n = blockIdx.x * T_HIST + tid;
        double a0 = 0, a1 = 0, a2 = 0, a3 = 0, a4 = 0;
        if (n < N_NODES) {
            float2 v = ((const float2*)x)[n];
            double x0 = v.x, x1 = v.y;
            a0 = x0; a1 = x1; a2 = x0 * x0; a3 = x1 * x1; a4 = x0 * x1;
        }
        for (int off = 32; off; off >>= 1) {
            a0 += __shfl_down(a0, off);
            a1 += __shfl_down(a1, off);
            a2 += __shfl_down(a2, off);
            a3 += __shfl_down(a3, off);
            a4 += __shfl_down(a4, off);
        }
        int w = tid >> 6;
        if ((tid & 63) == 0) {
            sh[0][w] = a0; sh[1][w] = a1; sh[2][w] = a2; sh[3][w] = a3; sh[4][w] = a4;
        }
        __syncthreads();
        if (tid == 0) {
            double t0 = 0, t1 = 0, t2 = 0, t3 = 0, t4 = 0;
            for (int i = 0; i < T_HIST / 64; i++) {
                t0 += sh[0][i]; t1 += sh[1][i]; t2 += sh[2][i]; t3 += sh[3][i]; t4 += sh[4][i];
            }
            atomicAdd(&stats[0], t0);
            atomicAdd(&stats[1], t1);
            atomicAdd(&stats[2], t2);
            atomicAdd(&stats[3], t3);
            atomicAdd(&stats[4], t4);
        }
    }
}

// ---- K2: encoder: gs[n] = dinv * (GB + sum_c PReLU(Ax0+Bx1+C) U[c]) ----
__global__ void encoder_kernel(const float* __restrict__ x,
                               const double* __restrict__ stats,
                               const float* __restrict__ w1, const float* __restrict__ b1,
                               const float* __restrict__ gamma, const float* __restrict__ beta,
                               const float* __restrict__ prelu_a,
                               const float* __restrict__ w2, const float* __restrict__ b2,
                               const float* __restrict__ gcn_w, const float* __restrict__ wb,
                               const float* __restrict__ degf,
                               float* __restrict__ dinv, float* __restrict__ gs,
                               float* __restrict__ acc) {
    __shared__ float sA[32], sB[32], sC[32], sV[32], sU[32];
    __shared__ float sGB;
    if (threadIdx.x < 32) {
        int c = threadIdx.x;
        double invN = 1.0 / (double)N_NODES;
        double m0 = stats[0] * invN, m1 = stats[1] * invN;
        double e00 = stats[2] * invN, e11 = stats[3] * invN, e01 = stats[4] * invN;
        double a = w1[2 * c], b = w1[2 * c + 1], t = b1[c];
        double meanH = a * m0 + b * m1 + t;
        double eh2 = a * a * e00 + b * b * e11 + 2.0 * a * b * e01 +
                     2.0 * t * (a * m0 + b * m1) + t * t;
        double var = eh2 - meanH * meanH;
        double inv = 1.0 / sqrt(var + 1e-5);
        float sc = (float)((double)gamma[c] * inv);
        float shift = beta[c] - (float)meanH * sc;
        sA[c] = (float)a * sc;
        sB[c] = (float)b * sc;
        sC[c] = (float)t * sc + shift;
        float vc = 0.f;
        for (int j = 0; j < 32; j++) vc += wb[j] * gcn_w[j * 32 + c];
        sV[c] = vc;
        float gb = b2[c] * vc;
        for (int off = 16; off; off >>= 1) gb += __shfl_down(gb, off, 32);
        if (c == 0) sGB = gb;
    }
    __syncthreads();
    if (threadIdx.x < 32) {
        float u = 0.f;
        for (int c = 0; c < 32; c++) u += sV[c] * w2[c * 32 + threadIdx.x];
        sU[threadIdx.x] = u;
    }
    __syncthreads();
    float alpha = prelu_a[0];
    int n = blockIdx.x * blockDim.x + threadIdx.x;
    if (n < N_NODES) {
        float2 xv = ((const float2*)x)[n];
        float g = sGB;
#pragma unroll
        for (int c = 0; c < 32; c++) {
            float hb = sA[c] * xv.x + sB[c] * xv.y + sC[c];
            float pc = hb >= 0.f ? hb : alpha * hb;
            g += pc * sU[c];
        }
        float di = rsqrtf(degf[n] + 1.0f);
        float gg = di * g;
        dinv[n] = di;
        gs[n] = gg;
        acc[n] = gg;  // self-loop term; finalize multiplies by dinv
    }
}

// ---- K3: scatter histogram straight from int64 src/dst ----
__global__ __launch_bounds__(T_HIST) void scatter_kernel(
        const void* __restrict__ ei, const float* __restrict__ gs,
        float* __restrict__ acc) {
    __shared__ float hist[PART];
    bool is64 = detect_is64(ei);
    const int tid = threadIdx.x;
    const int p = blockIdx.x >> 6;       // XCD-locality mapping (was bid&3)
    const int slice = blockIdx.x & 63;   // (was bid>>2)
    const int base = p * PART;

    for (int i = tid; i < PART; i += T_HIST) hist[i] = 0.f;
    __syncthreads();

    int q0 = slice * SLICE_Q, q1 = q0 + SLICE_Q;
    if (is64) {
        const longlong2* sq = (const longlong2*)((const long long*)ei);
        const longlong2* dq = (const longlong2*)((const long long*)ei + N_EDGES);
#define SCE(sa, sb, da, db) { \
        unsigned l0 = (unsigned)((int)(da).x - base); \
        unsigned l1 = (unsigned)((int)(da).y - base); \
        unsigned l2 = (unsigned)((int)(db).x - base); \
        unsigned l3 = (unsigned)((int)(db).y - base); \
        if (l0 < PART) atomicAdd(&hist[l0], gs[(int)(sa).x]); \
        if (l1 < PART) atomicAdd(&hist[l1], gs[(int)(sa).y]); \
        if (l2 < PART) atomicAdd(&hist[l2], gs[(int)(sb).x]); \
        if (l3 < PART) atomicAdd(&hist[l3], gs[(int)(sb).y]); }
        int qb = q0;
        for (; qb + 2 * T_HIST <= q1; qb += 2 * T_HIST) {
            longlong2 sa0 = sq[2 * (qb + tid)],          sa1 = sq[2 * (qb + tid) + 1];
            longlong2 da0 = dq[2 * (qb + tid)],          da1 = dq[2 * (qb + tid) + 1];
            longlong2 sb0 = sq[2 * (qb + T_HIST + tid)], sb1 = sq[2 * (qb + T_HIST + tid) + 1];
            longlong2 db0 = dq[2 * (qb + T_HIST + tid)], db1 = dq[2 * (qb + T_HIST + tid) + 1];
            SCE(sa0, sa1, da0, da1)
            SCE(sb0, sb1, db0, db1)
        }
        for (int q = qb + tid; q < q1; q += T_HIST) {
            longlong2 sa0 = sq[2 * q], sa1 = sq[2 * q + 1];
            longlong2 da0 = dq[2 * q], da1 = dq[2 * q + 1];
            SCE(sa0, sa1, da0, da1)
        }
#undef SCE
    } else {
        const int4* sq = (const int4*)((const int*)ei);
        const int4* dq = (const int4*)((const int*)ei + N_EDGES);
#define SC4(S, D) { \
        unsigned l0 = (unsigned)((D).x - base); \
        unsigned l1 = (unsigned)((D).y - base); \
        unsigned l2 = (unsigned)((D).z - base); \
        unsigned l3 = (unsigned)((D).w - base); \
        if (l0 < PART) atomicAdd(&hist[l0], gs[(S).x]); \
        if (l1 < PART) atomicAdd(&hist[l1], gs[(S).y]); \
        if (l2 < PART) atomicAdd(&hist[l2], gs[(S).z]); \
        if (l3 < PART) atomicAdd(&hist[l3], gs[(S).w]); }
        int qb = q0;
        for (; qb + 2 * T_HIST <= q1; qb += 2 * T_HIST) {
            int4 sa = sq[qb + tid];
            int4 da = dq[qb + tid];
            int4 sb = sq[qb + T_HIST + tid];
            int4 db = dq[qb + T_HIST + tid];
            SC4(sa, da) SC4(sb, db)
        }
        for (int q = qb + tid; q < q1; q += T_HIST) {
            int4 sa = sq[q];
            int4 da = dq[q];
            SC4(sa, da)
        }
#undef SC4
    }
    __syncthreads();
    for (int i = tid; i < PART; i += T_HIST) {
        float v = hist[i];
        if (v != 0.f) unsafeAtomicAdd(&acc[base + i], v);
    }
}

// ---- K4: finalize: out = dinv*acc + const ----
__global__ void finalize_kernel(const float* __restrict__ dinv, const float* __restrict__ acc,
                                const float* __restrict__ gcn_b, const float* __restrict__ wb,
                                const float* __restrict__ bb, float* __restrict__ out) {
    __shared__ float scc;
    if (threadIdx.x < 32) {
        float pv = wb[threadIdx.x] * gcn_b[threadIdx.x];
        for (int off = 16; off; off >>= 1) pv += __shfl_down(pv, off, 32);
        if (threadIdx.x == 0) scc = pv + bb[0];
    }
    __syncthreads();
    int n = blockIdx.x * blockDim.x + threadIdx.x;
    if (n < N_NODES) out[n] = dinv[n] * acc[n] + scc;
}

extern "C" void kernel_launch(void* const* d_in, const int* in_sizes, int n_in,
                              void* d_out, int out_size, void* d_ws, size_t ws_size,
                              hipStream_t stream) {
    const float* x       = (const float*)d_in[0];
    const void*  ei      = d_in[1];
    const float* w1      = (const float*)d_in[2];
    const float* b1      = (const float*)d_in[3];
    const float* bn_g    = (const float*)d_in[4];
    const float* bn_b    = (const float*)d_in[5];
    const float* prelu_a = (const float*)d_in[6];
    const float* w2      = (const float*)d_in[7];
    const float* b2      = (const float*)d_in[8];
    const float* gcn_w   = (const float*)d_in[9];
    const float* gcn_b   = (const float*)d_in[10];
    const float* wb      = (const float*)d_in[11];
    const float* bb      = (const float*)d_in[12];
    float* out = (float*)d_out;

    char* base = (char*)d_ws;
    double* stats = (double*)(base + OFF_STATS);
    float*  degf  = (float*)(base + OFF_DEG);
    float*  acc   = (float*)(base + OFF_ACC);
    float*  dinv  = (float*)(base + OFF_DINV);
    float*  gs    = (float*)(base + OFF_GS);

    // zero stats + degf (acc[0,N) fully written by encoder; hist zero-skip covers the rest)
    hipMemsetAsync(d_ws, 0, OFF_DEG + PART * P_PARTS * 4, stream);

    stats_deg_kernel<<<BLOCKS_H, T_HIST, 0, stream>>>(x, ei, stats, degf);
    encoder_kernel<<<(N_NODES + 255) / 256, 256, 0, stream>>>(
        x, stats, w1, b1, bn_g, bn_b, prelu_a, w2, b2, gcn_w, wb, degf, dinv, gs, acc);
    scatter_kernel<<<BLOCKS_H, T_HIST, 0, stream>>>(ei, gs, acc);
    finalize_kernel<<<(N_NODES + 255) / 256, 256, 0, stream>>>(dinv, acc, gcn_b, wb, bb, out);
}